// Round 5
// baseline (456.354 us; speedup 1.0000x reference)
//
#include <hip/hip_runtime.h>
#include <hip/hip_bf16.h>
#include <stdint.h>

#define E_   16
#define T_   512
#define KTOP 8
#define H_   2048
#define I_   1024
#define TK_  4096

typedef __attribute__((ext_vector_type(4))) int i32x4;

// ---- ws layout (bytes) ----
#define OFF_CNT     0                          // u32[16]
#define OFF_ROWMAX  4096                       // u32[4096]
#define OFF_XQ      32768                      // i8 [512][2048] = 1MB
#define OFF_S0      (OFF_XQ + T_*H_)           // f32[512]
#define OFF_S1      (OFF_S0 + 4096)            // f32[4096]
#define OFF_LIST    (OFF_S1 + TK_*4)           // i32[16][4096]
#define OFF_ACT     (OFF_LIST + E_*TK_*4)      // f32[4096][1024] = 16MB
#define OFF_AQ      (OFF_ACT + (size_t)TK_*I_*4)  // i8[4096][1024] = 4MB
#define OFF_Y2      (OFF_AQ + (size_t)TK_*I_)     // bf16[4096][2048] = 16MB

// ---------------- zero counts + rowmax ----------------
__global__ void k_zero(unsigned int* __restrict__ p) {
  int i = blockIdx.x * 256 + threadIdx.x;
  if (i < 5120) p[i] = 0;   // counts(16) + gap + rowmax(4096)
}

// ---------------- dynamic quant of x -> int8 (+ fused scatter) ----------------
__global__ void k_quant(const float* __restrict__ x, signed char* __restrict__ xq,
                        float* __restrict__ s0, const int* __restrict__ eids,
                        unsigned int* __restrict__ counts, int* __restrict__ row_list) {
  int t = blockIdx.x, tid = threadIdx.x;
  if (tid < KTOP) {
    int e = eids[t * KTOP + tid];
    int pos = (int)atomicAdd(&counts[e], 1u);
    row_list[e * TK_ + pos] = t * KTOP + tid;
  }
  const float4* xr = (const float4*)(x + (size_t)t * H_);
  float4 a = xr[tid * 2 + 0], b = xr[tid * 2 + 1];
  float m = fmaxf(
      fmaxf(fmaxf(fabsf(a.x), fabsf(a.y)), fmaxf(fabsf(a.z), fabsf(a.w))),
      fmaxf(fmaxf(fabsf(b.x), fabsf(b.y)), fmaxf(fabsf(b.z), fabsf(b.w))));
  for (int o = 32; o > 0; o >>= 1) m = fmaxf(m, __shfl_xor(m, o));
  __shared__ float wm[4];
  if ((tid & 63) == 0) wm[tid >> 6] = m;
  __syncthreads();
  m = fmaxf(fmaxf(wm[0], wm[1]), fmaxf(wm[2], wm[3]));
  float s = m / 127.0f;
  if (!(s > 0.f)) s = 1.0f;
  if (tid == 0) s0[t] = s;
  float v[8] = {a.x, a.y, a.z, a.w, b.x, b.y, b.z, b.w};
  unsigned int lo = 0, hi = 0;
#pragma unroll
  for (int j = 0; j < 4; ++j) {
    float qf = fminf(fmaxf(rintf(v[j] / s), -128.f), 127.f);
    lo |= ((unsigned)((int)qf & 0xFF)) << (8 * j);
  }
#pragma unroll
  for (int j = 0; j < 4; ++j) {
    float qf = fminf(fmaxf(rintf(v[4 + j] / s), -128.f), 127.f);
    hi |= ((unsigned)((int)qf & 0xFF)) << (8 * j);
  }
  ((uint2*)(xq + (size_t)t * H_))[tid] = make_uint2(lo, hi);
}

// ---------------- register helpers ----------------
__device__ __forceinline__ i32x4 packb(const int* s) {
  i32x4 r;
#pragma unroll
  for (int d = 0; d < 4; ++d)
    r[d] = (s[4 * d] & 0xFF) | ((s[4 * d + 1] & 0xFF) << 8) |
           ((s[4 * d + 2] & 0xFF) << 16) | (s[4 * d + 3] << 24);
  return r;
}

#define LOADA(BANK, TT)                                                   \
  _Pragma("unroll")                                                       \
  for (int i_ = 0; i_ < 5; ++i_)                                          \
    BANK[i_] = *(const i32x4*)(gA[i_] + (TT) * 64);

#define LOADB(BL, BR, TT)                                                 \
  _Pragma("unroll")                                                       \
  for (int j_ = 0; j_ < 16; ++j_) {                                       \
    BL[j_] = weL[(size_t)((TT) * 64 + j_) * 2048];                        \
    BR[j_] = weR[(size_t)((TT) * 64 + j_) * 2048];                        \
  }

#define COMP(AB, BL, BR)                                                  \
  do {                                                                    \
    i32x4 fL_ = packb(BL), fR_ = packb(BR);                               \
    _Pragma("unroll")                                                     \
    for (int i_ = 0; i_ < 5; ++i_) {                                      \
      acc[i_][0] = __builtin_amdgcn_mfma_i32_16x16x64_i8(                 \
          AB[i_], fL_, acc[i_][0], 0, 0, 0);                              \
      acc[i_][1] = __builtin_amdgcn_mfma_i32_16x16x64_i8(                 \
          AB[i_], fR_, acc[i_][1], 0, 0, 0);                              \
    }                                                                     \
  } while (0)

// ---------------- grouped GEMM1 + SwiGLU + rowmax ----------------
// one wave per block; wave tile = 80 rows x 16 act-cols (16 left + 16 right w-cols)
__launch_bounds__(64, 2)
__global__ void k_gemm1(const signed char* __restrict__ xq, const int* __restrict__ w1,
                        const float* __restrict__ ws1, const float* __restrict__ s0,
                        const unsigned int* __restrict__ counts,
                        const int* __restrict__ row_list,
                        float* __restrict__ act, unsigned int* __restrict__ rowmax) {
  int strip = blockIdx.x;          // 0..63 -> act cols strip*16..+15
  int e = blockIdx.y;
  int cnt = (int)counts[e];
  int p0 = strip * 16;
  const int* rl = row_list + e * TK_;
  const int* we = w1 + (size_t)e * H_ * (2 * I_);
  const float* wsc = ws1 + (size_t)e * (2 * I_);

  int lane = threadIdx.x & 63;
  int l15 = lane & 15, l4 = lane >> 4;

  const int* weL = we + (size_t)(l4 * 16) * 2048 + p0 + l15;
  const int* weR = weL + I_;

  for (int ch = blockIdx.z; ch * 80 < cnt; ch += 5) {
    int rbase = ch * 80;
    const signed char* gA[5];
#pragma unroll
    for (int i = 0; i < 5; ++i) {
      int gr = rbase + i * 16 + l15;
      int tok = rl[gr < cnt ? gr : 0] >> 3;
      gA[i] = xq + (size_t)tok * H_ + l4 * 16;
    }
    i32x4 acc[5][2];
#pragma unroll
    for (int i = 0; i < 5; ++i) { acc[i][0] = (i32x4)(0); acc[i][1] = (i32x4)(0); }

    i32x4 a0[5], a1[5];
    int b0L[16], b0R[16], b1L[16], b1R[16];

    LOADA(a0, 0);
    LOADB(b0L, b0R, 0);
    for (int t = 0; t < 32; t += 2) {
      LOADA(a1, t + 1);
      LOADB(b1L, b1R, t + 1);
      COMP(a0, b0L, b0R);
      int p2 = (t + 2 < 32) ? (t + 2) : t;   // dead reload on last pair
      LOADA(a0, p2);
      LOADB(b0L, b0R, p2);
      COMP(a1, b1L, b1R);
    }

    // epilogue: dequant + SwiGLU + rowmax (no cross-lane for SwiGLU: L/R same lane)
#pragma unroll
    for (int mi = 0; mi < 5; ++mi) {
#pragma unroll
      for (int r = 0; r < 4; ++r) {
        int gr = rbase + mi * 16 + l4 * 4 + r;
        bool valid = gr < cnt;
        int irow = rl[valid ? gr : 0];
        float s0v = s0[irow >> 3];
        float yl = (float)acc[mi][0][r] * wsc[p0 + l15] * s0v;
        float yr = (float)acc[mi][1][r] * wsc[I_ + p0 + l15] * s0v;
        float actv = (yl / (1.f + expf(-yl))) * yr;
        float rowm = fabsf(actv);
        rowm = fmaxf(rowm, __shfl_xor(rowm, 1));
        rowm = fmaxf(rowm, __shfl_xor(rowm, 2));
        rowm = fmaxf(rowm, __shfl_xor(rowm, 4));
        rowm = fmaxf(rowm, __shfl_xor(rowm, 8));
        if (valid) {
          act[(size_t)irow * I_ + p0 + l15] = actv;
          if (l15 == 0) atomicMax(rowmax + irow, __float_as_uint(rowm));
        }
      }
    }
  }
}

// ---------------- requant act -> int8 + s1 ----------------
__global__ void k_requant(const float* __restrict__ act, const unsigned int* __restrict__ rowmax,
                          signed char* __restrict__ aq, float* __restrict__ s1) {
  int i = blockIdx.x, tid = threadIdx.x;
  float m = __uint_as_float(rowmax[i]);
  float s = (m > 0.f) ? (m / 127.0f) : 1.0f;
  if (tid == 0) s1[i] = s;
  float4 v = ((const float4*)(act + (size_t)i * I_))[tid];
  float vv[4] = {v.x, v.y, v.z, v.w};
  unsigned int pk = 0;
#pragma unroll
  for (int j = 0; j < 4; ++j) {
    float qf = fminf(fmaxf(rintf(vv[j] / s), -128.f), 127.f);
    pk |= ((unsigned)((int)qf & 0xFF)) << (8 * j);
  }
  ((unsigned int*)(aq + (size_t)i * I_))[tid] = pk;
}

// ---------------- grouped GEMM2 + dequant + es fold -> bf16 ----------------
// one wave per block; wave tile = 80 rows x 32 cols (two 16-col frags)
__launch_bounds__(64, 2)
__global__ void k_gemm2(const signed char* __restrict__ aq, const int* __restrict__ w2,
                        const float* __restrict__ ws2, const float* __restrict__ s1,
                        const float* __restrict__ es,
                        const unsigned int* __restrict__ counts,
                        const int* __restrict__ row_list,
                        __hip_bfloat16* __restrict__ y2h) {
  int strip = blockIdx.x;          // 0..63 -> cols strip*32..+31
  int e = blockIdx.y;
  int cnt = (int)counts[e];
  int n0 = strip * 32;
  const int* rl = row_list + e * TK_;
  const int* we = w2 + (size_t)e * I_ * H_;
  const float* wsc = ws2 + (size_t)e * H_;

  int lane = threadIdx.x & 63;
  int l15 = lane & 15, l4 = lane >> 4;

  const int* weL = we + (size_t)(l4 * 16) * 2048 + n0 + l15;
  const int* weR = weL + 16;

  for (int ch = blockIdx.z; ch * 80 < cnt; ch += 5) {
    int rbase = ch * 80;
    const signed char* gA[5];
#pragma unroll
    for (int i = 0; i < 5; ++i) {
      int gr = rbase + i * 16 + l15;
      gA[i] = aq + (size_t)rl[gr < cnt ? gr : 0] * I_ + l4 * 16;
    }
    i32x4 acc[5][2];
#pragma unroll
    for (int i = 0; i < 5; ++i) { acc[i][0] = (i32x4)(0); acc[i][1] = (i32x4)(0); }

    i32x4 a0[5], a1[5];
    int b0L[16], b0R[16], b1L[16], b1R[16];

    LOADA(a0, 0);
    LOADB(b0L, b0R, 0);
    for (int t = 0; t < 16; t += 2) {
      LOADA(a1, t + 1);
      LOADB(b1L, b1R, t + 1);
      COMP(a0, b0L, b0R);
      int p2 = (t + 2 < 16) ? (t + 2) : t;
      LOADA(a0, p2);
      LOADB(b0L, b0R, p2);
      COMP(a1, b1L, b1R);
    }

#pragma unroll
    for (int mi = 0; mi < 5; ++mi) {
#pragma unroll
      for (int r = 0; r < 4; ++r) {
        int gr = rbase + mi * 16 + l4 * 4 + r;
        if (gr < cnt) {
          int irow = rl[gr];
          float sc = s1[irow] * es[irow];
#pragma unroll
          for (int n = 0; n < 2; ++n) {
            int c = n0 + n * 16 + l15;
            float v = (float)acc[mi][n][r] * wsc[c] * sc;
            y2h[(size_t)irow * H_ + c] = __float2bfloat16(v);
          }
        }
      }
    }
  }
}

// ---------------- combine (es already folded) ----------------
__global__ void k_combine(const __hip_bfloat16* __restrict__ y2h, float* __restrict__ out) {
  int idx = blockIdx.x * 256 + threadIdx.x;   // each handles 8 h
  int t = idx >> 8;
  int h0 = (idx & 255) * 8;
  float s[8];
#pragma unroll
  for (int j = 0; j < 8; ++j) s[j] = 0.f;
#pragma unroll
  for (int k = 0; k < KTOP; ++k) {
    const __hip_bfloat16* p = y2h + ((size_t)(t * KTOP + k) * H_ + h0);
    uint4 u = *(const uint4*)p;
    const __hip_bfloat16* b = (const __hip_bfloat16*)&u;
#pragma unroll
    for (int j = 0; j < 8; ++j) s[j] += __bfloat162float(b[j]);
  }
  float4 o0 = make_float4(s[0], s[1], s[2], s[3]);
  float4 o1 = make_float4(s[4], s[5], s[6], s[7]);
  float4* dst = (float4*)(out + (size_t)t * H_ + h0);
  dst[0] = o0; dst[1] = o1;
}

extern "C" void kernel_launch(void* const* d_in, const int* in_sizes, int n_in,
                              void* d_out, int out_size, void* d_ws, size_t ws_size,
                              hipStream_t stream) {
  const float* x   = (const float*)d_in[0];
  const int*   eid = (const int*)d_in[1];
  const int*   w1  = (const int*)d_in[2];
  const float* ws1 = (const float*)d_in[3];
  const int*   w2  = (const int*)d_in[4];
  const float* ws2 = (const float*)d_in[5];
  const float* es  = (const float*)d_in[7];
  float* out = (float*)d_out;
  char* ws = (char*)d_ws;

  unsigned int*  counts   = (unsigned int*)(ws + OFF_CNT);
  unsigned int*  rowmax   = (unsigned int*)(ws + OFF_ROWMAX);
  signed char*   xq       = (signed char*)(ws + OFF_XQ);
  float*         s0       = (float*)(ws + OFF_S0);
  float*         s1       = (float*)(ws + OFF_S1);
  int*           row_list = (int*)(ws + OFF_LIST);
  float*         act      = (float*)(ws + OFF_ACT);
  signed char*   aq       = (signed char*)(ws + OFF_AQ);
  __hip_bfloat16* y2h     = (__hip_bfloat16*)(ws + OFF_Y2);

  k_zero<<<20, 256, 0, stream>>>((unsigned int*)ws);
  k_quant<<<T_, 256, 0, stream>>>(x, xq, s0, eid, counts, row_list);
  k_gemm1<<<dim3(64, E_, 5), 64, 0, stream>>>(xq, w1, ws1, s0, counts, row_list, act, rowmax);
  k_requant<<<TK_, 256, 0, stream>>>(act, rowmax, aq, s1);
  k_gemm2<<<dim3(64, E_, 5), 64, 0, stream>>>(aq, w2, ws2, s1, es, counts, row_list, y2h);
  k_combine<<<(T_ * H_ / 8) / 256, 256, 0, stream>>>(y2h, out);
}

// Round 6
// 183.383 us; speedup vs baseline: 2.4885x; 2.4885x over previous
//
#include <hip/hip_runtime.h>
#include <hip/hip_bf16.h>
#include <stdint.h>

#define E_   16
#define T_   512
#define KTOP 8
#define H_   2048
#define I_   1024
#define TK_  4096

typedef __attribute__((ext_vector_type(4))) int i32x4;

// ---- ws layout (bytes) ----
#define OFF_CNT     0                          // u32[16]
#define OFF_ROWMAX  4096                       // u32[4096]
#define OFF_XQ      32768                      // i8 [512][2048] = 1MB
#define OFF_S0      (OFF_XQ + T_*H_)           // f32[512]
#define OFF_S1      (OFF_S0 + 4096)            // f32[4096]
#define OFF_LIST    (OFF_S1 + TK_*4)           // i32[16][4096]
#define OFF_ACT     (OFF_LIST + E_*TK_*4)      // f32[4096][1024] = 16MB
#define OFF_AQ      (OFF_ACT + (size_t)TK_*I_*4)  // i8[4096][1024] = 4MB
#define OFF_Y2      (OFF_AQ + (size_t)TK_*I_)     // bf16[4096][2048] = 16MB

#define SCHEDB() __builtin_amdgcn_sched_barrier(0)
#define VMCNT26() asm volatile("s_waitcnt vmcnt(26)" ::: "memory")
#define LGKM0()   asm volatile("s_waitcnt lgkmcnt(0)" ::: "memory")
#define BAR()     __builtin_amdgcn_s_barrier()

// ---------------- zero counts + rowmax ----------------
__global__ void k_zero(unsigned int* __restrict__ p) {
  int i = blockIdx.x * 256 + threadIdx.x;
  if (i < 5120) p[i] = 0;   // counts(16) + gap + rowmax(4096)
}

// ---------------- dynamic quant of x -> int8 (+ fused scatter) ----------------
__global__ void k_quant(const float* __restrict__ x, signed char* __restrict__ xq,
                        float* __restrict__ s0, const int* __restrict__ eids,
                        unsigned int* __restrict__ counts, int* __restrict__ row_list) {
  int t = blockIdx.x, tid = threadIdx.x;
  if (tid < KTOP) {
    int e = eids[t * KTOP + tid];
    int pos = (int)atomicAdd(&counts[e], 1u);
    row_list[e * TK_ + pos] = t * KTOP + tid;
  }
  const float4* xr = (const float4*)(x + (size_t)t * H_);
  float4 a = xr[tid * 2 + 0], b = xr[tid * 2 + 1];
  float m = fmaxf(
      fmaxf(fmaxf(fabsf(a.x), fabsf(a.y)), fmaxf(fabsf(a.z), fabsf(a.w))),
      fmaxf(fmaxf(fabsf(b.x), fabsf(b.y)), fmaxf(fabsf(b.z), fabsf(b.w))));
  for (int o = 32; o > 0; o >>= 1) m = fmaxf(m, __shfl_xor(m, o));
  __shared__ float wm[4];
  if ((tid & 63) == 0) wm[tid >> 6] = m;
  __syncthreads();
  m = fmaxf(fmaxf(wm[0], wm[1]), fmaxf(wm[2], wm[3]));
  float s = m / 127.0f;
  if (!(s > 0.f)) s = 1.0f;
  if (tid == 0) s0[t] = s;
  float v[8] = {a.x, a.y, a.z, a.w, b.x, b.y, b.z, b.w};
  unsigned int lo = 0, hi = 0;
#pragma unroll
  for (int j = 0; j < 4; ++j) {
    float qf = fminf(fmaxf(rintf(v[j] / s), -128.f), 127.f);
    lo |= ((unsigned)((int)qf & 0xFF)) << (8 * j);
  }
#pragma unroll
  for (int j = 0; j < 4; ++j) {
    float qf = fminf(fmaxf(rintf(v[4 + j] / s), -128.f), 127.f);
    hi |= ((unsigned)((int)qf & 0xFF)) << (8 * j);
  }
  ((uint2*)(xq + (size_t)t * H_))[tid] = make_uint2(lo, hi);
}

// ---------------- grouped GEMM common ----------------
#define BM_   320
#define WSTR  2048    // B k-row stride in ints (both gemms)

#define PACKW(SRC, DST) do {                                              \
    i32x4 pk_;                                                            \
    _Pragma("unroll")                                                     \
    for (int d_ = 0; d_ < 4; ++d_)                                        \
      pk_[d_] = ((SRC)[4*d_] & 0xFF) | (((SRC)[4*d_+1] & 0xFF) << 8) |    \
                (((SRC)[4*d_+2] & 0xFF) << 16) | ((SRC)[4*d_+3] << 24);   \
    *(i32x4*)(DST) = pk_;                                                 \
  } while (0)

#define LOADB(BANK, TT)                                                   \
    _Pragma("unroll")                                                     \
    for (int j_ = 0; j_ < 16; ++j_)                                       \
      BANK[j_] = bsrc[(size_t)((TT) * 64 + j_) * WSTR];

#define LOADAR(BANK, TT)                                                  \
    _Pragma("unroll")                                                     \
    for (int i_ = 0; i_ < 5; ++i_)                                        \
      BANK[i_] = *(const i32x4*)(gA[i_] + (TT) * 64);

#define MFMAS(ABANK, P)                                                   \
    _Pragma("unroll")                                                     \
    for (int n_ = 0; n_ < 4; ++n_) {                                      \
      i32x4 bf_ = *(const i32x4*)(bsm + (P) * 4096 + l4 * 1024 +          \
                                  (n_ * 16 + l15) * 16);                  \
      _Pragma("unroll")                                                   \
      for (int i_ = 0; i_ < 5; ++i_)                                      \
        acc[i_][n_] = __builtin_amdgcn_mfma_i32_16x16x64_i8(              \
            ABANK[i_], bf_, acc[i_][n_], 0, 0, 0);                        \
    }

// tile body: issue B(t+2)->BBANK, MFMA(t) from ABANK+LDS[P], issue A(t+2)->ABANK,
// then (unless LAST) vmcnt(26) + pack PKBANK (=B(t+1)) -> LDS[P^1] + barrier.
#define TILE(TT, P, ABANK, BBANK, PKBANK, NT, LAST) do {                  \
    int tn_ = (TT) + 2; if (tn_ > (NT) - 1) tn_ = (NT) - 1;               \
    SCHEDB();                                                             \
    LOADB(BBANK, tn_);                                                    \
    SCHEDB();                                                             \
    MFMAS(ABANK, P);                                                      \
    SCHEDB();                                                             \
    LOADAR(ABANK, tn_);                                                   \
    SCHEDB();                                                             \
    if (!(LAST)) {                                                        \
      VMCNT26(); SCHEDB();                                                \
      PACKW(PKBANK, bsm + ((P) ^ 1) * 4096 + bkg * 1024 + bc * 16);       \
      LGKM0(); BAR(); SCHEDB();                                           \
    }                                                                     \
  } while (0)

// ---------------- grouped GEMM1 + SwiGLU + rowmax ----------------
__launch_bounds__(256, 2)
__global__ void k_gemm1(const signed char* __restrict__ xq, const int* __restrict__ w1,
                        const float* __restrict__ ws1, const float* __restrict__ s0,
                        const unsigned int* __restrict__ counts,
                        const int* __restrict__ row_list,
                        float* __restrict__ act, unsigned int* __restrict__ rowmax) {
  __shared__ alignas(16) char bsm[2 * 4096];
  int e = blockIdx.y;
  int cnt = (int)counts[e];
  if (cnt == 0) return;
  int p0 = blockIdx.x * 32;
  const int* rl = row_list + e * TK_;
  const int* we = w1 + (size_t)e * H_ * (2 * I_);
  const float* wsc = ws1 + (size_t)e * (2 * I_);

  int tid = threadIdx.x, w = tid >> 6, lane = tid & 63;
  int l15 = lane & 15, l4 = lane >> 4;
  int bc = tid & 63, bkg = tid >> 6;
  int bgcol = (bc < 32) ? (p0 + bc) : (I_ + p0 + (bc - 32));
  const int* bsrc = we + (size_t)(bkg * 16) * WSTR + bgcol;

  const int NT = H_ / 64;   // 32
  int nch = (cnt + BM_ - 1) / BM_;
  for (int ch = 0; ch < nch; ++ch) {
    if (ch) { BAR(); }      // protect LDS reuse across chunks
    int rbase = ch * BM_;
    const signed char* gA[5];
#pragma unroll
    for (int i = 0; i < 5; ++i) {
      int gr = rbase + w * 80 + i * 16 + l15;
      int tok = rl[gr < cnt ? gr : 0] >> 3;
      gA[i] = xq + (size_t)tok * H_ + l4 * 16;
    }
    i32x4 acc[5][4];
#pragma unroll
    for (int i = 0; i < 5; ++i)
#pragma unroll
      for (int n = 0; n < 4; ++n) acc[i][n] = (i32x4)(0);

    i32x4 aR0[5], aR1[5];
    int bR0[16], bR1[16];
    // prologue: B(0), A(0), A(1), B(1); drain B(0) only; pack -> LDS buf0
    SCHEDB();
    LOADB(bR0, 0);
    SCHEDB();
    LOADAR(aR0, 0);
    LOADAR(aR1, 1);
    SCHEDB();
    LOADB(bR1, 1);
    SCHEDB();
    VMCNT26(); SCHEDB();
    PACKW(bR0, bsm + bkg * 1024 + bc * 16);
    LGKM0(); BAR(); SCHEDB();

    for (int t = 0; t < NT; t += 2) {
      TILE(t,     0, aR0, bR0, bR1, NT, false);
      TILE(t + 1, 1, aR1, bR1, bR0, NT, (t + 2 >= NT));
    }

    // epilogue: dequant + SwiGLU + rowmax
#pragma unroll
    for (int mi = 0; mi < 5; ++mi) {
#pragma unroll
      for (int r = 0; r < 4; ++r) {
        int gr = rbase + w * 80 + mi * 16 + l4 * 4 + r;
        bool valid = gr < cnt;
        int irow = rl[valid ? gr : 0];
        float s0v = s0[irow >> 3];
        float rowm = 0.f, av0 = 0.f, av1 = 0.f;
#pragma unroll
        for (int n = 0; n < 2; ++n) {
          int colL = p0 + n * 16 + l15;
          float yl = (float)acc[mi][n][r] * wsc[colL] * s0v;
          float yr = (float)acc[mi][n + 2][r] * wsc[I_ + colL] * s0v;
          float actv = (yl / (1.f + expf(-yl))) * yr;
          if (n == 0) av0 = actv; else av1 = actv;
          rowm = fmaxf(rowm, fabsf(actv));
        }
        rowm = fmaxf(rowm, __shfl_xor(rowm, 1));
        rowm = fmaxf(rowm, __shfl_xor(rowm, 2));
        rowm = fmaxf(rowm, __shfl_xor(rowm, 4));
        rowm = fmaxf(rowm, __shfl_xor(rowm, 8));
        if (valid) {
          act[(size_t)irow * I_ + p0 + l15] = av0;
          act[(size_t)irow * I_ + p0 + 16 + l15] = av1;
          if (l15 == 0) atomicMax(rowmax + irow, __float_as_uint(rowm));
        }
      }
    }
  }
}

// ---------------- requant act -> int8 + s1 ----------------
__global__ void k_requant(const float* __restrict__ act, const unsigned int* __restrict__ rowmax,
                          signed char* __restrict__ aq, float* __restrict__ s1) {
  int i = blockIdx.x, tid = threadIdx.x;
  float m = __uint_as_float(rowmax[i]);
  float s = (m > 0.f) ? (m / 127.0f) : 1.0f;
  if (tid == 0) s1[i] = s;
  float4 v = ((const float4*)(act + (size_t)i * I_))[tid];
  float vv[4] = {v.x, v.y, v.z, v.w};
  unsigned int pk = 0;
#pragma unroll
  for (int j = 0; j < 4; ++j) {
    float qf = fminf(fmaxf(rintf(vv[j] / s), -128.f), 127.f);
    pk |= ((unsigned)((int)qf & 0xFF)) << (8 * j);
  }
  ((unsigned int*)(aq + (size_t)i * I_))[tid] = pk;
}

// ---------------- grouped GEMM2 + dequant + es fold -> bf16 ----------------
__launch_bounds__(256, 2)
__global__ void k_gemm2(const signed char* __restrict__ aq, const int* __restrict__ w2,
                        const float* __restrict__ ws2, const float* __restrict__ s1,
                        const float* __restrict__ es,
                        const unsigned int* __restrict__ counts,
                        const int* __restrict__ row_list,
                        __hip_bfloat16* __restrict__ y2h) {
  __shared__ alignas(16) char bsm[2 * 4096];
  int e = blockIdx.y;
  int cnt = (int)counts[e];
  if (cnt == 0) return;
  int n0 = blockIdx.x * 64;
  const int* rl = row_list + e * TK_;
  const int* we = w2 + (size_t)e * I_ * H_;
  const float* wsc = ws2 + (size_t)e * H_;

  int tid = threadIdx.x, w = tid >> 6, lane = tid & 63;
  int l15 = lane & 15, l4 = lane >> 4;
  int bc = tid & 63, bkg = tid >> 6;
  const int* bsrc = we + (size_t)(bkg * 16) * WSTR + n0 + bc;

  const int NT = I_ / 64;   // 16
  int nch = (cnt + BM_ - 1) / BM_;
  for (int ch = 0; ch < nch; ++ch) {
    if (ch) { BAR(); }
    int rbase = ch * BM_;
    const signed char* gA[5];
#pragma unroll
    for (int i = 0; i < 5; ++i) {
      int gr = rbase + w * 80 + i * 16 + l15;
      gA[i] = aq + (size_t)rl[gr < cnt ? gr : 0] * I_ + l4 * 16;
    }
    i32x4 acc[5][4];
#pragma unroll
    for (int i = 0; i < 5; ++i)
#pragma unroll
      for (int n = 0; n < 4; ++n) acc[i][n] = (i32x4)(0);

    i32x4 aR0[5], aR1[5];
    int bR0[16], bR1[16];
    SCHEDB();
    LOADB(bR0, 0);
    SCHEDB();
    LOADAR(aR0, 0);
    LOADAR(aR1, 1);
    SCHEDB();
    LOADB(bR1, 1);
    SCHEDB();
    VMCNT26(); SCHEDB();
    PACKW(bR0, bsm + bkg * 1024 + bc * 16);
    LGKM0(); BAR(); SCHEDB();

    for (int t = 0; t < NT; t += 2) {
      TILE(t,     0, aR0, bR0, bR1, NT, false);
      TILE(t + 1, 1, aR1, bR1, bR0, NT, (t + 2 >= NT));
    }

#pragma unroll
    for (int mi = 0; mi < 5; ++mi) {
#pragma unroll
      for (int r = 0; r < 4; ++r) {
        int gr = rbase + w * 80 + mi * 16 + l4 * 4 + r;
        if (gr < cnt) {
          int irow = rl[gr];
          float sc = s1[irow] * es[irow];
#pragma unroll
          for (int n = 0; n < 4; ++n) {
            int c = n0 + n * 16 + l15;
            float v = (float)acc[mi][n][r] * wsc[c] * sc;
            y2h[(size_t)irow * H_ + c] = __float2bfloat16(v);
          }
        }
      }
    }
  }
}

// ---------------- combine (es already folded) ----------------
__global__ void k_combine(const __hip_bfloat16* __restrict__ y2h, float* __restrict__ out) {
  int idx = blockIdx.x * 256 + threadIdx.x;   // each handles 8 h
  int t = idx >> 8;
  int h0 = (idx & 255) * 8;
  float s[8];
#pragma unroll
  for (int j = 0; j < 8; ++j) s[j] = 0.f;
#pragma unroll
  for (int k = 0; k < KTOP; ++k) {
    const __hip_bfloat16* p = y2h + ((size_t)(t * KTOP + k) * H_ + h0);
    uint4 u = *(const uint4*)p;
    const __hip_bfloat16* b = (const __hip_bfloat16*)&u;
#pragma unroll
    for (int j = 0; j < 8; ++j) s[j] += __bfloat162float(b[j]);
  }
  float4 o0 = make_float4(s[0], s[1], s[2], s[3]);
  float4 o1 = make_float4(s[4], s[5], s[6], s[7]);
  float4* dst = (float4*)(out + (size_t)t * H_ + h0);
  dst[0] = o0; dst[1] = o1;
}

extern "C" void kernel_launch(void* const* d_in, const int* in_sizes, int n_in,
                              void* d_out, int out_size, void* d_ws, size_t ws_size,
                              hipStream_t stream) {
  const float* x   = (const float*)d_in[0];
  const int*   eid = (const int*)d_in[1];
  const int*   w1  = (const int*)d_in[2];
  const float* ws1 = (const float*)d_in[3];
  const int*   w2  = (const int*)d_in[4];
  const float* ws2 = (const float*)d_in[5];
  const float* es  = (const float*)d_in[7];
  float* out = (float*)d_out;
  char* ws = (char*)d_ws;

  unsigned int*  counts   = (unsigned int*)(ws + OFF_CNT);
  unsigned int*  rowmax   = (unsigned int*)(ws + OFF_ROWMAX);
  signed char*   xq       = (signed char*)(ws + OFF_XQ);
  float*         s0       = (float*)(ws + OFF_S0);
  float*         s1       = (float*)(ws + OFF_S1);
  int*           row_list = (int*)(ws + OFF_LIST);
  float*         act      = (float*)(ws + OFF_ACT);
  signed char*   aq       = (signed char*)(ws + OFF_AQ);
  __hip_bfloat16* y2h     = (__hip_bfloat16*)(ws + OFF_Y2);

  k_zero<<<20, 256, 0, stream>>>((unsigned int*)ws);
  k_quant<<<T_, 256, 0, stream>>>(x, xq, s0, eid, counts, row_list);
  k_gemm1<<<dim3(32, E_), 256, 0, stream>>>(xq, w1, ws1, s0, counts, row_list, act, rowmax);
  k_requant<<<TK_, 256, 0, stream>>>(act, rowmax, aq, s1);
  k_gemm2<<<dim3(32, E_), 256, 0, stream>>>(aq, w2, ws2, s1, es, counts, row_list, y2h);
  k_combine<<<(T_ * H_ / 8) / 256, 256, 0, stream>>>(y2h, out);
}